// Round 14
// baseline (650.461 us; speedup 1.0000x reference)
//
#include <hip/hip_runtime.h>
#include <math.h>

#define NLEN   32768
#define NATOMS 256
#define ATOM_S 512
#define NSTEPS 16
#define NCHAN  8   // 2 signals x 4 batches
#define NSEL   (NCHAN * NSTEPS)   // 128

// 8-replica LDS geometry (ushort units)
#define SPO   680                  // elements per split within a replica
#define REPS  (3 * SPO)            // 2040 ushort per replica (splits b1,b2,b3)
#define REPT  (8 * REPS)           // 16320 ushort total = 32640 B

typedef unsigned short ushort_t;
typedef __attribute__((ext_vector_type(8))) short bf16x8;
typedef __attribute__((ext_vector_type(16))) float f32x16;
#define MFMA32 __builtin_amdgcn_mfma_f32_32x32x16_bf16

// ---------- packed ordered key helpers ----------
__device__ __forceinline__ unsigned int ord32(float x) {
    unsigned int u = __float_as_uint(x);
    return (u & 0x80000000u) ? ~u : (u | 0x80000000u);
}
__device__ __forceinline__ float unord32(unsigned int o) {
    unsigned int u = (o & 0x80000000u) ? (o & 0x7FFFFFFFu) : ~o;
    return __uint_as_float(u);
}
// bigger key = bigger v, then smaller atom, then smaller position
__device__ __forceinline__ unsigned long long packkey(float v, int a, int q) {
    return ((unsigned long long)ord32(v) << 23)
         | ((unsigned long long)((255 - a) & 255) << 15)
         | (unsigned long long)((NLEN - 1 - q) & 32767);
}

// ---------- bf16 split helpers (RNE) ----------
__device__ __forceinline__ ushort_t f2bf(float x) {
    unsigned int u = __float_as_uint(x);
    unsigned int r = u + 0x7FFFu + ((u >> 16) & 1u);
    return (ushort_t)(r >> 16);
}
__device__ __forceinline__ float bf2f(ushort_t b) {
    return __uint_as_float(((unsigned int)b) << 16);
}

// ---------- prep: normalize dict; write FRAGMENT-MAJOR bf16 splits ----------
__global__ void prep_kernel(const float* __restrict__ recon,
                            const float* __restrict__ target,
                            const float* __restrict__ d,
                            float* __restrict__ d_t,
                            ushort_t* __restrict__ dA1,
                            ushort_t* __restrict__ dA2,
                            ushort_t* __restrict__ dA3,
                            float* __restrict__ res0,
                            float* __restrict__ res1,
                            unsigned long long* __restrict__ mkey,
                            unsigned long long* __restrict__ stepkey) {
    int b = blockIdx.x, t = threadIdx.x;
    if (b < NATOMS) {
        __shared__ float red[256];
        float x0 = d[b * ATOM_S + t];
        float x1 = d[b * ATOM_S + 256 + t];
        red[t] = x0 * x0 + x1 * x1;
        __syncthreads();
        for (int off = 128; off; off >>= 1) {
            if (t < off) red[t] += red[t + off];
            __syncthreads();
        }
        float denom = sqrtf(red[0]) + 1e-8f;
        float xn0 = x0 / denom, xn1 = x1 / denom;
        int s0 = t, s1 = t + 256;
        d_t[((s0 >> 2) * NATOMS + b) * 4 + (s0 & 3)] = xn0;
        d_t[((s1 >> 2) * NATOMS + b) * 4 + (s1 & 3)] = xn1;
        {
            ushort_t a1 = f2bf(xn0); float r1 = xn0 - bf2f(a1);
            ushort_t a2 = f2bf(r1);  float r2 = r1 - bf2f(a2);
            ushort_t a3 = f2bf(r2);
            int fi = ((s0 >> 3) * NATOMS + b) * 8 + (s0 & 7);
            dA1[fi] = a1; dA2[fi] = a2; dA3[fi] = a3;
        }
        {
            ushort_t a1 = f2bf(xn1); float r1 = xn1 - bf2f(a1);
            ushort_t a2 = f2bf(r1);  float r2 = r1 - bf2f(a2);
            ushort_t a3 = f2bf(r2);
            int fi = ((s1 >> 3) * NATOMS + b) * 8 + (s1 & 7);
            dA1[fi] = a1; dA2[fi] = a2; dA3[fi] = a3;
        }
    } else if (b < NATOMS + 32) {
        int blk = b - NATOMS;
        for (int i = 0; i < 32; ++i) {
            int idx = blk * 8192 + i * 256 + t;     // 0 .. 262143
            int c = idx >> 15, q = idx & (NLEN - 1);
            float x = (c < 4) ? recon[c * NLEN + q] : target[(c - 4) * NLEN + q];
            res0[idx] = x;
            res1[idx] = x;
            mkey[idx] = 0ull;                        // needed: init uses atomicMax
        }
    } else {
        if (t < NSEL) stepkey[t] = 0ull;
    }
}

// ---------- fragment loaders ----------
__device__ __forceinline__ bf16x8 ldfragA(const ushort_t* __restrict__ dg, int off) {
    union { uint4 u4; bf16x8 v; } f;
    f.u4 = *(const uint4*)(dg + off);       // 16B-aligned, wave-contiguous
    return f.v;
}
__device__ __forceinline__ bf16x8 ldB128(const ushort_t* p) {
    union { uint4 u4; bf16x8 v; } f;
    f.u4 = *(const uint4*)p;                // 16B-aligned by replica construction
    return f.v;
}

// ---------- stage one fp32 value into the 8-replica split LDS ----------
__device__ __forceinline__ void stage_rep(float x, int i, ushort_t* rep) {
    ushort_t b1 = f2bf(x);  float x1 = x - bf2f(b1);
    ushort_t b2 = f2bf(x1); float x2 = x1 - bf2f(b2);
    ushort_t b3 = f2bf(x2);
#pragma unroll
    for (int o = 0; o < 8; ++o) {
        int j = i - o;
        if (j >= 0) {
            ushort_t* rp = rep + o * REPS + j;
            rp[0]       = b1;
            rp[SPO]     = b2;
            rp[2 * SPO] = b3;
        }
    }
}

// ---------- MFMA conv tile: AT*32 atoms x NT*32 positions per wave ----------
// Per-acc product order A1B1,A1B2,A2B1,A2B2,A1B3,A3B1, ks ascending -> bitwise
// identical to rounds 9-13. B via ds_read_b128 (8-replica LDS, +bofs wave-col
// offset, multiple of 8); A via fragment-major coalesced global loads.
template<int AT, int NT, bool APF>
__device__ __forceinline__ void conv_body(const ushort_t* __restrict__ dA1,
                                          const ushort_t* __restrict__ dA2,
                                          const ushort_t* __restrict__ dA3,
                                          const ushort_t* rep,
                                          int a0w, int lr, int lk, int bofs,
                                          f32x16 acc[AT][NT]) {
#pragma unroll
    for (int at = 0; at < AT; ++at)
#pragma unroll
        for (int nt = 0; nt < NT; ++nt) acc[at][nt] = (f32x16)(0.0f);

    int ab[AT];
#pragma unroll
    for (int at = 0; at < AT; ++at)
        ab[at] = (((lk >> 3) * NATOMS) + a0w + at * 32 + lr) * 8;

    bf16x8 A1[AT], A2[AT], A3[AT];
    if (APF) {
#pragma unroll
        for (int at = 0; at < AT; ++at) {
            A1[at] = ldfragA(dA1, ab[at]);
            A2[at] = ldfragA(dA2, ab[at]);
            A3[at] = ldfragA(dA3, ab[at]);
        }
    }

#pragma unroll 1
    for (int ks = 0; ks < 32; ++ks) {
        if (!APF) {
#pragma unroll
            for (int at = 0; at < AT; ++at) {
                A1[at] = ldfragA(dA1, ab[at]);
                A2[at] = ldfragA(dA2, ab[at]);
                A3[at] = ldfragA(dA3, ab[at]);
            }
        }
        int s00 = ks * 16 + lr + lk;
        int o = s00 & 7, jb = s00 & ~7;
        const ushort_t* rb = rep + o * REPS + jb + bofs;

        bf16x8 B1[NT], B2[NT], B3[NT];
#pragma unroll
        for (int nt = 0; nt < NT; ++nt) {
            B1[nt] = ldB128(rb + nt * 32);
            B2[nt] = ldB128(rb + SPO + nt * 32);
        }
        bf16x8 nA1[AT], nA2[AT], nA3[AT];
        if (APF && ks < 31) {
#pragma unroll
            for (int at = 0; at < AT; ++at) {
                nA1[at] = ldfragA(dA1, ab[at] + 2 * NATOMS * 8);
                nA2[at] = ldfragA(dA2, ab[at] + 2 * NATOMS * 8);
                nA3[at] = ldfragA(dA3, ab[at] + 2 * NATOMS * 8);
            }
        }
#pragma unroll
        for (int at = 0; at < AT; ++at)
#pragma unroll
            for (int nt = 0; nt < NT; ++nt)
                acc[at][nt] = MFMA32(A1[at], B1[nt], acc[at][nt], 0, 0, 0);
#pragma unroll
        for (int at = 0; at < AT; ++at)
#pragma unroll
            for (int nt = 0; nt < NT; ++nt)
                acc[at][nt] = MFMA32(A1[at], B2[nt], acc[at][nt], 0, 0, 0);
#pragma unroll
        for (int at = 0; at < AT; ++at)
#pragma unroll
            for (int nt = 0; nt < NT; ++nt)
                acc[at][nt] = MFMA32(A2[at], B1[nt], acc[at][nt], 0, 0, 0);
#pragma unroll
        for (int at = 0; at < AT; ++at)
#pragma unroll
            for (int nt = 0; nt < NT; ++nt)
                acc[at][nt] = MFMA32(A2[at], B2[nt], acc[at][nt], 0, 0, 0);
#pragma unroll
        for (int nt = 0; nt < NT; ++nt) B3[nt] = ldB128(rb + 2 * SPO + nt * 32);
#pragma unroll
        for (int at = 0; at < AT; ++at)
#pragma unroll
            for (int nt = 0; nt < NT; ++nt)
                acc[at][nt] = MFMA32(A1[at], B3[nt], acc[at][nt], 0, 0, 0);
#pragma unroll
        for (int at = 0; at < AT; ++at)
#pragma unroll
            for (int nt = 0; nt < NT; ++nt)
                acc[at][nt] = MFMA32(A3[at], B1[nt], acc[at][nt], 0, 0, 0);
        if (APF && ks < 31) {
#pragma unroll
            for (int at = 0; at < AT; ++at) {
                A1[at] = nA1[at]; A2[at] = nA2[at]; A3[at] = nA3[at];
            }
        }
#pragma unroll
        for (int at = 0; at < AT; ++at) ab[at] += 2 * NATOMS * 8;
    }
}

// ---------- initial full correlation via bf16-split MFMA ----------
// grid (256 pos-tiles of 128, 8 channels, 2 atom-halves), 256 threads = 4 waves.
// wave wid: wa = wid&1 (atom sub-half of 64), wn = wid>>1 (pos col of 64).
// AT=2 x NT=2: 64 atoms x 64 positions per wave, 6 B-loads + 6 A-loads per ks.
__global__ __launch_bounds__(256) void init_mfma(const float* __restrict__ res,
                                                 const ushort_t* __restrict__ dA1,
                                                 const ushort_t* __restrict__ dA2,
                                                 const ushort_t* __restrict__ dA3,
                                                 unsigned long long* __restrict__ mkey,
                                                 unsigned long long* __restrict__ stepkey) {
    __shared__ __align__(16) ushort_t rep[REPT];
    __shared__ unsigned long long warr[256];
    __shared__ unsigned long long kred[256];
    int t = threadIdx.x;
    int qt = blockIdx.x * 128;
    int c  = blockIdx.y;
    int half = blockIdx.z;

    const float* rc_ = res + c * NLEN;
    for (int i = t; i < 656; i += 256) {
        int g = qt + i;
        float x = (g < NLEN) ? rc_[g] : 0.0f;
        stage_rep(x, i, rep);
    }
    __syncthreads();

    int wid = t >> 6, l = t & 63;
    int wa = wid & 1, wn = wid >> 1;
    int a0w = half * 128 + wa * 64;
    int lk = (l >> 5) * 8;
    int lr = l & 31;
    int qtw = qt + wn * 64;

    f32x16 acc[2][2];
    conv_body<2, 2, true>(dA1, dA2, dA3, rep, a0w, lr, lk, wn * 64, acc);

    // C/D mapping (m74/m101): col=lane&31, row=(reg&3)+8*(reg>>2)+4*(lane>>5)
#pragma unroll
    for (int nt = 0; nt < 2; ++nt) {
        unsigned long long key = 0ull;
#pragma unroll
        for (int at = 0; at < 2; ++at)
#pragma unroll
            for (int reg = 0; reg < 16; ++reg) {
                int atom = a0w + at * 32 + (reg & 3) + 8 * (reg >> 2) + 4 * (l >> 5);
                unsigned long long kk2 = packkey(acc[at][nt][reg], atom, qtw + nt * 32 + lr);
                if (kk2 > key) key = kk2;
            }
        unsigned long long o = __shfl_xor(key, 32);
        if (o > key) key = o;
        if (l < 32) warr[wid * 64 + nt * 32 + l] = key;
    }
    __syncthreads();

    if (t < 128) {
        int wn2 = t >> 6, off = t & 63;
        unsigned long long f = warr[wn2 * 128 + off];
        if (warr[wn2 * 128 + 64 + off] > f) f = warr[wn2 * 128 + 64 + off];
        atomicMax(&mkey[c * NLEN + qt + t], f);
        kred[t] = f;
    } else kred[t] = 0ull;
    __syncthreads();
    for (int off = 128; off; off >>= 1) {
        if (t < off) { if (kred[t + off] > kred[t]) kred[t] = kred[t + off]; }
        __syncthreads();
    }
    if (t == 0) atomicMax(&stepkey[c], kred[0]);
}

// ---------- per-step kernel: 512 blocks x 256 threads (unchanged from R13) ----------
__global__ __launch_bounds__(256) void step_kernel(const float* __restrict__ buf_cur,
                                                   float* __restrict__ buf_next,
                                                   const float* __restrict__ d_t,
                                                   const ushort_t* __restrict__ dA1,
                                                   const ushort_t* __restrict__ dA2,
                                                   const ushort_t* __restrict__ dA3,
                                                   unsigned long long* __restrict__ mkey,
                                                   unsigned long long* __restrict__ stepkey,
                                                   int k) {
    int b = blockIdx.x, t = threadIdx.x;
    __shared__ __align__(16) ushort_t rep[REPT];
    __shared__ unsigned long long warr[128];
    __shared__ unsigned long long kred[256];

    if (b < 256) {
        int c = b >> 5, tile = b & 31;
        unsigned long long key = stepkey[k * NCHAN + c];
        int a = 255 - (int)((key >> 15) & 255);
        int p = (NLEN - 1) - (int)(key & 32767);
        float v = unord32((unsigned int)(key >> 23));
        int w0 = max(0, p - (ATOM_S - 1));
        int w1 = min(NLEN, p + ATOM_S);
        int qt = w0 + tile * 32;

        const float* rcur = buf_cur + c * NLEN;
        for (int i = t; i < 656; i += 256) {
            int g = qt + i;
            float x = (g < NLEN) ? rcur[g] : 0.0f;
            int s = g - p;
            if (s >= 0 && s < ATOM_S && g < NLEN) {
                float dval = d_t[((s >> 2) * NATOMS + a) * 4 + (s & 3)];
                x = __fsub_rn(x, __fmul_rn(v, dval));
            }
            stage_rep(x, i, rep);
        }
        __syncthreads();

        int wid = t >> 6, l = t & 63;
        int a0w = wid * 64;
        int lk = (l >> 5) * 8;
        int lr = l & 31;

        f32x16 acc[2][1];
        conv_body<2, 1, true>(dA1, dA2, dA3, rep, a0w, lr, lk, 0, acc);

        unsigned long long kkey = 0ull;
#pragma unroll
        for (int at = 0; at < 2; ++at)
#pragma unroll
            for (int reg = 0; reg < 16; ++reg) {
                int atom = a0w + at * 32 + (reg & 3) + 8 * (reg >> 2) + 4 * (l >> 5);
                unsigned long long kk2 = packkey(acc[at][0][reg], atom, qt + lr);
                if (kk2 > kkey) kkey = kk2;
            }
        unsigned long long o = __shfl_xor(kkey, 32);
        if (o > kkey) kkey = o;
        if (l < 32) warr[wid * 32 + l] = kkey;
        __syncthreads();

        unsigned long long myk = 0ull;
        if (t < 32) {
            unsigned long long f = warr[t];
            if (warr[32 + t] > f) f = warr[32 + t];
            if (warr[64 + t] > f) f = warr[64 + t];
            if (warr[96 + t] > f) f = warr[96 + t];
            int q = qt + t;
            if (q < w1) {                     // exclusive owner: plain store
                mkey[c * NLEN + q] = f;
                myk = f;
            }
        }
        kred[t] = myk;
        __syncthreads();
        for (int off = 128; off; off >>= 1) {
            if (t < off) { if (kred[t + off] > kred[t]) kred[t] = kred[t + off]; }
            __syncthreads();
        }
        if (t == 0) atomicMax(&stepkey[(k + 1) * NCHAN + c], kred[0]);
    } else {
        int sb = b - 256;
        int c = sb >> 5, seg = sb & 31;
        unsigned long long key = stepkey[k * NCHAN + c];
        int p = (NLEN - 1) - (int)(key & 32767);
        int w0 = max(0, p - (ATOM_S - 1));
        int w1 = min(NLEN, p + ATOM_S);

        // writer duty: bring buf_next from R_{k-1} to R_{k+1} (sequential deltas)
        if (seg == 0) {
            float* bn = buf_next + c * NLEN;
            int s0 = (k > 0) ? (k - 1) : 0;
            for (int s = s0; s <= k; ++s) {
                unsigned long long ks = stepkey[s * NCHAN + c];
                int as = 255 - (int)((ks >> 15) & 255);
                int ps = (NLEN - 1) - (int)(ks & 32767);
                float vs = unord32((unsigned int)(ks >> 23));
                for (int i = t; i < ATOM_S; i += 256) {
                    int q = ps + i;
                    if (q < NLEN) {
                        float dval = d_t[((i >> 2) * NATOMS + as) * 4 + (i & 3)];
                        bn[q] = __fsub_rn(bn[q], __fmul_rn(vs, dval));
                    }
                }
                __syncthreads();
            }
        }

        // scan duty: max over mkey outside [w0,w1), 1024 positions
        const unsigned long long* mk = mkey + c * NLEN;
        unsigned long long myk = 0ull;
        int q0 = seg * 1024;
#pragma unroll
        for (int i = 0; i < 4; ++i) {
            int q = q0 + i * 256 + t;
            if (q < w0 || q >= w1) {
                unsigned long long z = mk[q];
                if (z > myk) myk = z;
            }
        }
        kred[t] = myk;
        __syncthreads();
        for (int off = 128; off; off >>= 1) {
            if (t < off) { if (kred[t + off] > kred[t]) kred[t] = kred[t + off]; }
            __syncthreads();
        }
        if (t == 0) atomicMax(&stepkey[(k + 1) * NCHAN + c], kred[0]);
    }
}

// ---------- final loss from stepkey (one block, 256 threads) ----------
__global__ __launch_bounds__(256) void loss_kernel(const unsigned long long* __restrict__ stepkey,
                                                   float* __restrict__ out) {
    int t = threadIdx.x;
    __shared__ int   lsa[NSEL], lsp[NSEL];
    __shared__ float lsv[NSEL];
    __shared__ double red[256];
    __shared__ double smx;

    if (t < NSEL) {
        int c = t >> 4, k = t & 15;
        unsigned long long key = stepkey[k * NCHAN + c];
        lsa[t] = 255 - (int)((key >> 15) & 255);
        lsp[t] = (NLEN - 1) - (int)(key & 32767);
        lsv[t] = unord32((unsigned int)(key >> 23));
    }
    __syncthreads();

    int myc = (t < NSEL) ? (t >> 4) : -1;
    int mya = (t < NSEL) ? lsa[t] : -1;
    int myp = (t < NSEL) ? lsp[t] : -1;

    int fullowner = t;
    double fullsum = 0.0;
    if (t < NSEL) {
        for (int j = 0; j < NSEL; ++j) {
            if ((j >> 4) == myc && lsa[j] == mya && lsp[j] == myp) {
                if (j < fullowner) fullowner = j;
                fullsum += (double)lsv[j];
            }
        }
    }
    red[t] = (t < NSEL && fullowner == t) ? fullsum : 0.0;
    __syncthreads();
    for (int off = 128; off; off >>= 1) {
        if (t < off) red[t] = fmax(red[t], red[t + off]);
        __syncthreads();
    }
    if (t == 0) smx = red[0];
    __syncthreads();
    double mx = smx;

    int gowner = t;
    double rv = 0.0, tv = 0.0;
    if (t < NSEL) {
        int myb = myc & 3;
        for (int j = 0; j < NSEL; ++j) {
            int jc = j >> 4;
            if ((jc & 3) == myb && lsa[j] == mya && lsp[j] == myp) {
                if (j < gowner) gowner = j;
                if (jc < 4) rv += (double)lsv[j]; else tv += (double)lsv[j];
            }
        }
    }

    const double EPS = 1e-12;
    double bg_term = -log1p(-EPS);

    double extra = 0.0;
    if (t < NSEL && gowner == t) {
        double r = rv / mx, tt = tv / mx;
        double rc = r;
        if (rc < EPS) rc = EPS;
        if (rc > 1.0) rc = 1.0;
        double lr = log(rc);  if (lr < -100.0) lr = -100.0;
        double l1 = (rc >= 1.0) ? -100.0 : log1p(-rc);
        if (l1 < -100.0) l1 = -100.0;
        double term = -(tt * lr + (1.0 - tt) * l1);
        extra = term - bg_term;
    }

    red[t] = extra;
    __syncthreads();
    for (int off = 128; off; off >>= 1) {
        if (t < off) red[t] += red[t + off];
        __syncthreads();
    }
    if (t == 0) {
        const double count = 33554432.0;  // 4 * 256 * 32768
        double total = count * bg_term + red[0];
        out[0] = (float)(total / count);
    }
}

// ---------- launch ----------
extern "C" void kernel_launch(void* const* d_in, const int* in_sizes, int n_in,
                              void* d_out, int out_size, void* d_ws, size_t ws_size,
                              hipStream_t stream) {
    const float* recon  = (const float*)d_in[0];
    const float* target = (const float*)d_in[1];
    const float* d      = (const float*)d_in[2];
    char* ws = (char*)d_ws;
    float* d_t                    = (float*)(ws);                        // 512 KB
    float* res0                   = (float*)(ws + 524288);               // 1 MB
    float* res1                   = (float*)(ws + 1572864);              // 1 MB
    unsigned long long* mkey      = (unsigned long long*)(ws + 2621440); // 2 MB
    unsigned long long* stepkey   = (unsigned long long*)(ws + 4718592); // 1 KB
    ushort_t* dA1                 = (ushort_t*)(ws + 4719616);           // 256 KB
    ushort_t* dA2                 = (ushort_t*)(ws + 4981760);           // 256 KB
    ushort_t* dA3                 = (ushort_t*)(ws + 5243904);           // 256 KB
    float* out = (float*)d_out;

    hipLaunchKernelGGL(prep_kernel, dim3(NATOMS + 33), dim3(256), 0, stream,
                       recon, target, d, d_t, dA1, dA2, dA3, res0, res1, mkey, stepkey);
    hipLaunchKernelGGL(init_mfma, dim3(256, NCHAN, 2), dim3(256), 0, stream,
                       res0, dA1, dA2, dA3, mkey, stepkey);
    for (int k = 0; k < NSTEPS - 1; ++k) {
        float* cur  = (k & 1) ? res1 : res0;
        float* next = (k & 1) ? res0 : res1;
        hipLaunchKernelGGL(step_kernel, dim3(512), dim3(256), 0, stream,
                           cur, next, d_t, dA1, dA2, dA3, mkey, stepkey, k);
    }
    hipLaunchKernelGGL(loss_kernel, dim3(1), dim3(256), 0, stream,
                       stepkey, out);
}

// Round 15
// 445.473 us; speedup vs baseline: 1.4602x; 1.4602x over previous
//
#include <hip/hip_runtime.h>
#include <math.h>

#define NLEN   32768
#define NATOMS 256
#define ATOM_S 512
#define NSTEPS 16
#define NCHAN  8   // 2 signals x 4 batches
#define NSEL   (NCHAN * NSTEPS)   // 128

// 8-replica LDS geometry (ushort units), fp16 2-way split
#define SPO   680                  // elements per split within a replica (1360 B, 16B-aligned)
#define REPS  (2 * SPO)            // 1360 ushort per replica (splits h1,h2)
#define REPT  (8 * REPS)           // 10880 ushort total = 21760 B

typedef unsigned short ushort_t;
typedef _Float16 half8 __attribute__((ext_vector_type(8)));
typedef __attribute__((ext_vector_type(16))) float f32x16;
#define MFMA32H __builtin_amdgcn_mfma_f32_32x32x16_f16

// ---------- packed ordered key helpers ----------
__device__ __forceinline__ unsigned int ord32(float x) {
    unsigned int u = __float_as_uint(x);
    return (u & 0x80000000u) ? ~u : (u | 0x80000000u);
}
__device__ __forceinline__ float unord32(unsigned int o) {
    unsigned int u = (o & 0x80000000u) ? (o & 0x7FFFFFFFu) : ~o;
    return __uint_as_float(u);
}
// bigger key = bigger v, then smaller atom, then smaller position
__device__ __forceinline__ unsigned long long packkey(float v, int a, int q) {
    return ((unsigned long long)ord32(v) << 23)
         | ((unsigned long long)((255 - a) & 255) << 15)
         | (unsigned long long)((NLEN - 1 - q) & 32767);
}

// ---------- fp16 split helpers (RNE) ----------
__device__ __forceinline__ ushort_t f2h(float x) {
    _Float16 h = (_Float16)x;
    return *(ushort_t*)&h;
}
__device__ __forceinline__ float h2f(ushort_t u) {
    _Float16 h = *(_Float16*)&u;
    return (float)h;
}

// ---------- prep: normalize dict; write FRAGMENT-MAJOR fp16 2-way splits ----------
// dH*[(kslot*NATOMS + atom)*8 + j] = split(d_n[atom][kslot*8 + j]), kslot=0..63.
__global__ void prep_kernel(const float* __restrict__ recon,
                            const float* __restrict__ target,
                            const float* __restrict__ d,
                            float* __restrict__ d_t,
                            ushort_t* __restrict__ dH1,
                            ushort_t* __restrict__ dH2,
                            float* __restrict__ res0,
                            float* __restrict__ res1,
                            unsigned long long* __restrict__ mkey,
                            unsigned long long* __restrict__ stepkey) {
    int b = blockIdx.x, t = threadIdx.x;
    if (b < NATOMS) {
        __shared__ float red[256];
        float x0 = d[b * ATOM_S + t];
        float x1 = d[b * ATOM_S + 256 + t];
        red[t] = x0 * x0 + x1 * x1;
        __syncthreads();
        for (int off = 128; off; off >>= 1) {
            if (t < off) red[t] += red[t + off];
            __syncthreads();
        }
        float denom = sqrtf(red[0]) + 1e-8f;
        float xn0 = x0 / denom, xn1 = x1 / denom;
        int s0 = t, s1 = t + 256;
        d_t[((s0 >> 2) * NATOMS + b) * 4 + (s0 & 3)] = xn0;
        d_t[((s1 >> 2) * NATOMS + b) * 4 + (s1 & 3)] = xn1;
        {
            ushort_t a1 = f2h(xn0); float r1 = xn0 - h2f(a1);
            ushort_t a2 = f2h(r1);
            int fi = ((s0 >> 3) * NATOMS + b) * 8 + (s0 & 7);
            dH1[fi] = a1; dH2[fi] = a2;
        }
        {
            ushort_t a1 = f2h(xn1); float r1 = xn1 - h2f(a1);
            ushort_t a2 = f2h(r1);
            int fi = ((s1 >> 3) * NATOMS + b) * 8 + (s1 & 7);
            dH1[fi] = a1; dH2[fi] = a2;
        }
    } else if (b < NATOMS + 32) {
        int blk = b - NATOMS;
        for (int i = 0; i < 32; ++i) {
            int idx = blk * 8192 + i * 256 + t;     // 0 .. 262143
            int c = idx >> 15, q = idx & (NLEN - 1);
            float x = (c < 4) ? recon[c * NLEN + q] : target[(c - 4) * NLEN + q];
            res0[idx] = x;
            res1[idx] = x;
            mkey[idx] = 0ull;                        // needed: init uses atomicMax
        }
    } else {
        if (t < NSEL) stepkey[t] = 0ull;
    }
}

// ---------- fragment loaders ----------
__device__ __forceinline__ half8 ldfragA(const ushort_t* __restrict__ dg, int off) {
    union { uint4 u4; half8 v; } f;
    f.u4 = *(const uint4*)(dg + off);       // 16B-aligned, wave-contiguous
    return f.v;
}
__device__ __forceinline__ half8 ldB128(const ushort_t* p) {
    union { uint4 u4; half8 v; } f;
    f.u4 = *(const uint4*)p;                // 16B-aligned by replica construction
    return f.v;
}

// ---------- stage one fp32 value into the 8-replica fp16-split LDS ----------
__device__ __forceinline__ void stage_rep(float x, int i, ushort_t* rep) {
    ushort_t h1 = f2h(x);  float x1 = x - h2f(h1);
    ushort_t h2 = f2h(x1);
#pragma unroll
    for (int o = 0; o < 8; ++o) {
        int j = i - o;
        if (j >= 0) {
            ushort_t* rp = rep + o * REPS + j;
            rp[0]   = h1;
            rp[SPO] = h2;
        }
    }
}

// ---------- MFMA conv tile: AT*32 atoms x NT*32 positions per wave ----------
// fp16 2-way split, 3 products per acc: A1B1, A1B2, A2B1 (ks ascending, fixed
// order -> deterministic). B via ds_read_b128 (8-replica LDS, +bofs wave-col
// offset, multiple of 8); A via fragment-major coalesced global loads.
template<int AT, int NT, bool APF>
__device__ __forceinline__ void conv_body(const ushort_t* __restrict__ dH1,
                                          const ushort_t* __restrict__ dH2,
                                          const ushort_t* rep,
                                          int a0w, int lr, int lk, int bofs,
                                          f32x16 acc[AT][NT]) {
#pragma unroll
    for (int at = 0; at < AT; ++at)
#pragma unroll
        for (int nt = 0; nt < NT; ++nt) acc[at][nt] = (f32x16)(0.0f);

    int ab[AT];
#pragma unroll
    for (int at = 0; at < AT; ++at)
        ab[at] = (((lk >> 3) * NATOMS) + a0w + at * 32 + lr) * 8;

    half8 A1[AT], A2[AT];
    if (APF) {
#pragma unroll
        for (int at = 0; at < AT; ++at) {
            A1[at] = ldfragA(dH1, ab[at]);
            A2[at] = ldfragA(dH2, ab[at]);
        }
    }

#pragma unroll 1
    for (int ks = 0; ks < 32; ++ks) {
        if (!APF) {
#pragma unroll
            for (int at = 0; at < AT; ++at) {
                A1[at] = ldfragA(dH1, ab[at]);
                A2[at] = ldfragA(dH2, ab[at]);
            }
        }
        int s00 = ks * 16 + lr + lk;
        int o = s00 & 7, jb = s00 & ~7;
        const ushort_t* rb = rep + o * REPS + jb + bofs;

        half8 B1[NT], B2[NT];
#pragma unroll
        for (int nt = 0; nt < NT; ++nt) {
            B1[nt] = ldB128(rb + nt * 32);
            B2[nt] = ldB128(rb + SPO + nt * 32);
        }
        half8 nA1[AT], nA2[AT];
        if (APF && ks < 31) {
#pragma unroll
            for (int at = 0; at < AT; ++at) {
                nA1[at] = ldfragA(dH1, ab[at] + 2 * NATOMS * 8);
                nA2[at] = ldfragA(dH2, ab[at] + 2 * NATOMS * 8);
            }
        }
#pragma unroll
        for (int at = 0; at < AT; ++at)
#pragma unroll
            for (int nt = 0; nt < NT; ++nt)
                acc[at][nt] = MFMA32H(A1[at], B1[nt], acc[at][nt], 0, 0, 0);
#pragma unroll
        for (int at = 0; at < AT; ++at)
#pragma unroll
            for (int nt = 0; nt < NT; ++nt)
                acc[at][nt] = MFMA32H(A1[at], B2[nt], acc[at][nt], 0, 0, 0);
#pragma unroll
        for (int at = 0; at < AT; ++at)
#pragma unroll
            for (int nt = 0; nt < NT; ++nt)
                acc[at][nt] = MFMA32H(A2[at], B1[nt], acc[at][nt], 0, 0, 0);
        if (APF && ks < 31) {
#pragma unroll
            for (int at = 0; at < AT; ++at) { A1[at] = nA1[at]; A2[at] = nA2[at]; }
        }
#pragma unroll
        for (int at = 0; at < AT; ++at) ab[at] += 2 * NATOMS * 8;
    }
}

// ---------- initial full correlation via fp16-split MFMA ----------
// grid (256 pos-tiles of 128, 8 channels, 2 atom-halves), 256 threads = 4 waves.
// wave w: atoms [half*128 + w*32, +32) x positions [qt, qt+128) (AT=1, NT=4).
__global__ __launch_bounds__(256) void init_mfma(const float* __restrict__ res,
                                                 const ushort_t* __restrict__ dH1,
                                                 const ushort_t* __restrict__ dH2,
                                                 unsigned long long* __restrict__ mkey,
                                                 unsigned long long* __restrict__ stepkey) {
    __shared__ __align__(16) ushort_t rep[REPT];
    __shared__ unsigned long long warr[512];
    __shared__ unsigned long long kred[256];
    int t = threadIdx.x;
    int qt = blockIdx.x * 128;
    int c  = blockIdx.y;
    int half = blockIdx.z;

    const float* rc_ = res + c * NLEN;
    for (int i = t; i < 656; i += 256) {
        int g = qt + i;
        float x = (g < NLEN) ? rc_[g] : 0.0f;
        stage_rep(x, i, rep);
    }
    __syncthreads();

    int wid = t >> 6, l = t & 63;
    int a0w = half * 128 + wid * 32;
    int lk = (l >> 5) * 8;
    int lr = l & 31;

    f32x16 acc[1][4];
    conv_body<1, 4, false>(dH1, dH2, rep, a0w, lr, lk, 0, acc);

    // C/D mapping (m74/m101): col=lane&31, row=(reg&3)+8*(reg>>2)+4*(lane>>5)
#pragma unroll
    for (int nt = 0; nt < 4; ++nt) {
        unsigned long long key = 0ull;
#pragma unroll
        for (int reg = 0; reg < 16; ++reg) {
            int atom = a0w + (reg & 3) + 8 * (reg >> 2) + 4 * (l >> 5);
            unsigned long long kk2 = packkey(acc[0][nt][reg], atom, qt + nt * 32 + lr);
            if (kk2 > key) key = kk2;
        }
        unsigned long long o = __shfl_xor(key, 32);
        if (o > key) key = o;
        if (l < 32) warr[wid * 128 + nt * 32 + l] = key;
    }
    __syncthreads();

    if (t < 128) {
        unsigned long long f = warr[t];
        if (warr[128 + t] > f) f = warr[128 + t];
        if (warr[256 + t] > f) f = warr[256 + t];
        if (warr[384 + t] > f) f = warr[384 + t];
        atomicMax(&mkey[c * NLEN + qt + t], f);
        kred[t] = f;
    } else kred[t] = 0ull;
    __syncthreads();
    for (int off = 128; off; off >>= 1) {
        if (t < off) { if (kred[t + off] > kred[t]) kred[t] = kred[t + off]; }
        __syncthreads();
    }
    if (t == 0) atomicMax(&stepkey[c], kred[0]);
}

// ---------- per-step kernel: 512 blocks x 256 threads (R13 structure) ----------
// b < 256 : window MFMA blocks: c = b>>5, tile = b&31, qt = w0 + tile*32.
//           4 waves x 64 atoms (AT=2) x 32 pos (NT=1); stage buf_cur + delta_k
//           on the fly (fp32, same rounding as writer); exclusive plain mkey stores.
// b >= 256: scan blocks: c = sb>>5, seg = sb&31 (1024 pos) outside [w0,w1);
//           seg==0 blocks also advance buf_next from R_{k-1} to R_{k+1} (fp32 exact).
__global__ __launch_bounds__(256) void step_kernel(const float* __restrict__ buf_cur,
                                                   float* __restrict__ buf_next,
                                                   const float* __restrict__ d_t,
                                                   const ushort_t* __restrict__ dH1,
                                                   const ushort_t* __restrict__ dH2,
                                                   unsigned long long* __restrict__ mkey,
                                                   unsigned long long* __restrict__ stepkey,
                                                   int k) {
    int b = blockIdx.x, t = threadIdx.x;
    __shared__ __align__(16) ushort_t rep[REPT];
    __shared__ unsigned long long warr[128];
    __shared__ unsigned long long kred[256];

    if (b < 256) {
        int c = b >> 5, tile = b & 31;
        unsigned long long key = stepkey[k * NCHAN + c];
        int a = 255 - (int)((key >> 15) & 255);
        int p = (NLEN - 1) - (int)(key & 32767);
        float v = unord32((unsigned int)(key >> 23));
        int w0 = max(0, p - (ATOM_S - 1));
        int w1 = min(NLEN, p + ATOM_S);
        int qt = w0 + tile * 32;

        const float* rcur = buf_cur + c * NLEN;
        for (int i = t; i < 656; i += 256) {
            int g = qt + i;
            float x = (g < NLEN) ? rcur[g] : 0.0f;
            int s = g - p;
            if (s >= 0 && s < ATOM_S && g < NLEN) {
                float dval = d_t[((s >> 2) * NATOMS + a) * 4 + (s & 3)];
                x = __fsub_rn(x, __fmul_rn(v, dval));
            }
            stage_rep(x, i, rep);
        }
        __syncthreads();

        int wid = t >> 6, l = t & 63;
        int a0w = wid * 64;
        int lk = (l >> 5) * 8;
        int lr = l & 31;

        f32x16 acc[2][1];
        conv_body<2, 1, true>(dH1, dH2, rep, a0w, lr, lk, 0, acc);

        unsigned long long kkey = 0ull;
#pragma unroll
        for (int at = 0; at < 2; ++at)
#pragma unroll
            for (int reg = 0; reg < 16; ++reg) {
                int atom = a0w + at * 32 + (reg & 3) + 8 * (reg >> 2) + 4 * (l >> 5);
                unsigned long long kk2 = packkey(acc[at][0][reg], atom, qt + lr);
                if (kk2 > kkey) kkey = kk2;
            }
        unsigned long long o = __shfl_xor(kkey, 32);
        if (o > kkey) kkey = o;
        if (l < 32) warr[wid * 32 + l] = kkey;
        __syncthreads();

        unsigned long long myk = 0ull;
        if (t < 32) {
            unsigned long long f = warr[t];
            if (warr[32 + t] > f) f = warr[32 + t];
            if (warr[64 + t] > f) f = warr[64 + t];
            if (warr[96 + t] > f) f = warr[96 + t];
            int q = qt + t;
            if (q < w1) {                     // exclusive owner: plain store
                mkey[c * NLEN + q] = f;
                myk = f;
            }
        }
        kred[t] = myk;
        __syncthreads();
        for (int off = 128; off; off >>= 1) {
            if (t < off) { if (kred[t + off] > kred[t]) kred[t] = kred[t + off]; }
            __syncthreads();
        }
        if (t == 0) atomicMax(&stepkey[(k + 1) * NCHAN + c], kred[0]);
    } else {
        int sb = b - 256;
        int c = sb >> 5, seg = sb & 31;
        unsigned long long key = stepkey[k * NCHAN + c];
        int p = (NLEN - 1) - (int)(key & 32767);
        int w0 = max(0, p - (ATOM_S - 1));
        int w1 = min(NLEN, p + ATOM_S);

        // writer duty: bring buf_next from R_{k-1} to R_{k+1} (sequential deltas)
        if (seg == 0) {
            float* bn = buf_next + c * NLEN;
            int s0 = (k > 0) ? (k - 1) : 0;
            for (int s = s0; s <= k; ++s) {
                unsigned long long ks = stepkey[s * NCHAN + c];
                int as = 255 - (int)((ks >> 15) & 255);
                int ps = (NLEN - 1) - (int)(ks & 32767);
                float vs = unord32((unsigned int)(ks >> 23));
                for (int i = t; i < ATOM_S; i += 256) {
                    int q = ps + i;
                    if (q < NLEN) {
                        float dval = d_t[((i >> 2) * NATOMS + as) * 4 + (i & 3)];
                        bn[q] = __fsub_rn(bn[q], __fmul_rn(vs, dval));
                    }
                }
                __syncthreads();
            }
        }

        // scan duty: max over mkey outside [w0,w1), 1024 positions
        const unsigned long long* mk = mkey + c * NLEN;
        unsigned long long myk = 0ull;
        int q0 = seg * 1024;
#pragma unroll
        for (int i = 0; i < 4; ++i) {
            int q = q0 + i * 256 + t;
            if (q < w0 || q >= w1) {
                unsigned long long z = mk[q];
                if (z > myk) myk = z;
            }
        }
        kred[t] = myk;
        __syncthreads();
        for (int off = 128; off; off >>= 1) {
            if (t < off) { if (kred[t + off] > kred[t]) kred[t] = kred[t + off]; }
            __syncthreads();
        }
        if (t == 0) atomicMax(&stepkey[(k + 1) * NCHAN + c], kred[0]);
    }
}

// ---------- final loss from stepkey (one block, 256 threads) ----------
__global__ __launch_bounds__(256) void loss_kernel(const unsigned long long* __restrict__ stepkey,
                                                   float* __restrict__ out) {
    int t = threadIdx.x;
    __shared__ int   lsa[NSEL], lsp[NSEL];
    __shared__ float lsv[NSEL];
    __shared__ double red[256];
    __shared__ double smx;

    if (t < NSEL) {
        int c = t >> 4, k = t & 15;
        unsigned long long key = stepkey[k * NCHAN + c];
        lsa[t] = 255 - (int)((key >> 15) & 255);
        lsp[t] = (NLEN - 1) - (int)(key & 32767);
        lsv[t] = unord32((unsigned int)(key >> 23));
    }
    __syncthreads();

    int myc = (t < NSEL) ? (t >> 4) : -1;
    int mya = (t < NSEL) ? lsa[t] : -1;
    int myp = (t < NSEL) ? lsp[t] : -1;

    int fullowner = t;
    double fullsum = 0.0;
    if (t < NSEL) {
        for (int j = 0; j < NSEL; ++j) {
            if ((j >> 4) == myc && lsa[j] == mya && lsp[j] == myp) {
                if (j < fullowner) fullowner = j;
                fullsum += (double)lsv[j];
            }
        }
    }
    red[t] = (t < NSEL && fullowner == t) ? fullsum : 0.0;
    __syncthreads();
    for (int off = 128; off; off >>= 1) {
        if (t < off) red[t] = fmax(red[t], red[t + off]);
        __syncthreads();
    }
    if (t == 0) smx = red[0];
    __syncthreads();
    double mx = smx;

    int gowner = t;
    double rv = 0.0, tv = 0.0;
    if (t < NSEL) {
        int myb = myc & 3;
        for (int j = 0; j < NSEL; ++j) {
            int jc = j >> 4;
            if ((jc & 3) == myb && lsa[j] == mya && lsp[j] == myp) {
                if (j < gowner) gowner = j;
                if (jc < 4) rv += (double)lsv[j]; else tv += (double)lsv[j];
            }
        }
    }

    const double EPS = 1e-12;
    double bg_term = -log1p(-EPS);

    double extra = 0.0;
    if (t < NSEL && gowner == t) {
        double r = rv / mx, tt = tv / mx;
        double rc = r;
        if (rc < EPS) rc = EPS;
        if (rc > 1.0) rc = 1.0;
        double lr = log(rc);  if (lr < -100.0) lr = -100.0;
        double l1 = (rc >= 1.0) ? -100.0 : log1p(-rc);
        if (l1 < -100.0) l1 = -100.0;
        double term = -(tt * lr + (1.0 - tt) * l1);
        extra = term - bg_term;
    }

    red[t] = extra;
    __syncthreads();
    for (int off = 128; off; off >>= 1) {
        if (t < off) red[t] += red[t + off];
        __syncthreads();
    }
    if (t == 0) {
        const double count = 33554432.0;  // 4 * 256 * 32768
        double total = count * bg_term + red[0];
        out[0] = (float)(total / count);
    }
}

// ---------- launch ----------
extern "C" void kernel_launch(void* const* d_in, const int* in_sizes, int n_in,
                              void* d_out, int out_size, void* d_ws, size_t ws_size,
                              hipStream_t stream) {
    const float* recon  = (const float*)d_in[0];
    const float* target = (const float*)d_in[1];
    const float* d      = (const float*)d_in[2];
    char* ws = (char*)d_ws;
    float* d_t                    = (float*)(ws);                        // 512 KB
    float* res0                   = (float*)(ws + 524288);               // 1 MB
    float* res1                   = (float*)(ws + 1572864);              // 1 MB
    unsigned long long* mkey      = (unsigned long long*)(ws + 2621440); // 2 MB
    unsigned long long* stepkey   = (unsigned long long*)(ws + 4718592); // 1 KB
    ushort_t* dH1                 = (ushort_t*)(ws + 4719616);           // 256 KB
    ushort_t* dH2                 = (ushort_t*)(ws + 4981760);           // 256 KB
    float* out = (float*)d_out;

    hipLaunchKernelGGL(prep_kernel, dim3(NATOMS + 33), dim3(256), 0, stream,
                       recon, target, d, d_t, dH1, dH2, res0, res1, mkey, stepkey);
    hipLaunchKernelGGL(init_mfma, dim3(256, NCHAN, 2), dim3(256), 0, stream,
                       res0, dH1, dH2, mkey, stepkey);
    for (int k = 0; k < NSTEPS - 1; ++k) {
        float* cur  = (k & 1) ? res1 : res0;
        float* next = (k & 1) ? res0 : res1;
        hipLaunchKernelGGL(step_kernel, dim3(512), dim3(256), 0, stream,
                           cur, next, d_t, dH1, dH2, mkey, stepkey, k);
    }
    hipLaunchKernelGGL(loss_kernel, dim3(1), dim3(256), 0, stream,
                       stepkey, out);
}

// Round 16
// 445.407 us; speedup vs baseline: 1.4604x; 1.0001x over previous
//
#include <hip/hip_runtime.h>
#include <math.h>

#define NLEN   32768
#define NATOMS 256
#define ATOM_S 512
#define NSTEPS 16
#define NCHAN  8   // 2 signals x 4 batches
#define NSEL   (NCHAN * NSTEPS)   // 128

// 8-replica LDS geometry (ushort units), fp16 2-way split.
// RSTR = 712 ushorts = 356 dwords; 356 % 32 == 4 -> replica o starts at bank
// 4*o, so an 8-lane replica group tiles all 32 banks exactly once per
// ds_read_b128: conflict-free. 712 % 8 == 0 keeps 16B alignment.
#define RSTR  712
#define H2OFF (8 * RSTR)           // second split region, bank-aligned
#define REPT  (16 * RSTR)          // 11392 ushort = 22784 B

typedef unsigned short ushort_t;
typedef _Float16 half8 __attribute__((ext_vector_type(8)));
typedef __attribute__((ext_vector_type(16))) float f32x16;
#define MFMA32H __builtin_amdgcn_mfma_f32_32x32x16_f16

// ---------- packed ordered key helpers ----------
__device__ __forceinline__ unsigned int ord32(float x) {
    unsigned int u = __float_as_uint(x);
    return (u & 0x80000000u) ? ~u : (u | 0x80000000u);
}
__device__ __forceinline__ float unord32(unsigned int o) {
    unsigned int u = (o & 0x80000000u) ? (o & 0x7FFFFFFFu) : ~o;
    return __uint_as_float(u);
}
// bigger key = bigger v, then smaller atom, then smaller position
__device__ __forceinline__ unsigned long long packkey(float v, int a, int q) {
    return ((unsigned long long)ord32(v) << 23)
         | ((unsigned long long)((255 - a) & 255) << 15)
         | (unsigned long long)((NLEN - 1 - q) & 32767);
}

// ---------- fp16 split helpers (RNE) ----------
__device__ __forceinline__ ushort_t f2h(float x) {
    _Float16 h = (_Float16)x;
    return *(ushort_t*)&h;
}
__device__ __forceinline__ float h2f(ushort_t u) {
    _Float16 h = *(_Float16*)&u;
    return (float)h;
}

// ---------- prep: normalize dict; write FRAGMENT-MAJOR fp16 2-way splits ----------
__global__ void prep_kernel(const float* __restrict__ recon,
                            const float* __restrict__ target,
                            const float* __restrict__ d,
                            float* __restrict__ d_t,
                            ushort_t* __restrict__ dH1,
                            ushort_t* __restrict__ dH2,
                            float* __restrict__ res0,
                            float* __restrict__ res1,
                            unsigned long long* __restrict__ mkey,
                            unsigned long long* __restrict__ stepkey) {
    int b = blockIdx.x, t = threadIdx.x;
    if (b < NATOMS) {
        __shared__ float red[256];
        float x0 = d[b * ATOM_S + t];
        float x1 = d[b * ATOM_S + 256 + t];
        red[t] = x0 * x0 + x1 * x1;
        __syncthreads();
        for (int off = 128; off; off >>= 1) {
            if (t < off) red[t] += red[t + off];
            __syncthreads();
        }
        float denom = sqrtf(red[0]) + 1e-8f;
        float xn0 = x0 / denom, xn1 = x1 / denom;
        int s0 = t, s1 = t + 256;
        d_t[((s0 >> 2) * NATOMS + b) * 4 + (s0 & 3)] = xn0;
        d_t[((s1 >> 2) * NATOMS + b) * 4 + (s1 & 3)] = xn1;
        {
            ushort_t a1 = f2h(xn0); float r1 = xn0 - h2f(a1);
            ushort_t a2 = f2h(r1);
            int fi = ((s0 >> 3) * NATOMS + b) * 8 + (s0 & 7);
            dH1[fi] = a1; dH2[fi] = a2;
        }
        {
            ushort_t a1 = f2h(xn1); float r1 = xn1 - h2f(a1);
            ushort_t a2 = f2h(r1);
            int fi = ((s1 >> 3) * NATOMS + b) * 8 + (s1 & 7);
            dH1[fi] = a1; dH2[fi] = a2;
        }
    } else if (b < NATOMS + 32) {
        int blk = b - NATOMS;
        for (int i = 0; i < 32; ++i) {
            int idx = blk * 8192 + i * 256 + t;     // 0 .. 262143
            int c = idx >> 15, q = idx & (NLEN - 1);
            float x = (c < 4) ? recon[c * NLEN + q] : target[(c - 4) * NLEN + q];
            res0[idx] = x;
            res1[idx] = x;
            mkey[idx] = 0ull;                        // needed: init uses atomicMax
        }
    } else {
        if (t < NSEL) stepkey[t] = 0ull;
    }
}

// ---------- fragment loaders ----------
__device__ __forceinline__ half8 ldfragA(const ushort_t* __restrict__ dg, int off) {
    union { uint4 u4; half8 v; } f;
    f.u4 = *(const uint4*)(dg + off);       // 16B-aligned, wave-contiguous
    return f.v;
}
__device__ __forceinline__ half8 ldB128(const ushort_t* p) {
    union { uint4 u4; half8 v; } f;
    f.u4 = *(const uint4*)p;                // 16B-aligned by replica construction
    return f.v;
}

// ---------- stage one fp32 value into the 8-replica fp16-split LDS ----------
__device__ __forceinline__ void stage_rep(float x, int i, ushort_t* rep) {
    ushort_t h1 = f2h(x);  float x1 = x - h2f(h1);
    ushort_t h2 = f2h(x1);
#pragma unroll
    for (int o = 0; o < 8; ++o) {
        int j = i - o;
        if (j >= 0) {
            rep[o * RSTR + j]         = h1;
            rep[H2OFF + o * RSTR + j] = h2;
        }
    }
}

// ---------- MFMA conv tile: AT*32 atoms x NT*32 positions per wave ----------
// fp16 2-way split, 3 products per acc: A1B1, A1B2, A2B1 (ks ascending, fixed
// order -> deterministic). B via conflict-free ds_read_b128 (8-replica LDS,
// stride RSTR); A via fragment-major coalesced global loads.
template<int AT, int NT, bool APF>
__device__ __forceinline__ void conv_body(const ushort_t* __restrict__ dH1,
                                          const ushort_t* __restrict__ dH2,
                                          const ushort_t* rep,
                                          int a0w, int lr, int lk, int bofs,
                                          f32x16 acc[AT][NT]) {
#pragma unroll
    for (int at = 0; at < AT; ++at)
#pragma unroll
        for (int nt = 0; nt < NT; ++nt) acc[at][nt] = (f32x16)(0.0f);

    int ab[AT];
#pragma unroll
    for (int at = 0; at < AT; ++at)
        ab[at] = (((lk >> 3) * NATOMS) + a0w + at * 32 + lr) * 8;

    half8 A1[AT], A2[AT];
    if (APF) {
#pragma unroll
        for (int at = 0; at < AT; ++at) {
            A1[at] = ldfragA(dH1, ab[at]);
            A2[at] = ldfragA(dH2, ab[at]);
        }
    }

#pragma unroll 1
    for (int ks = 0; ks < 32; ++ks) {
        if (!APF) {
#pragma unroll
            for (int at = 0; at < AT; ++at) {
                A1[at] = ldfragA(dH1, ab[at]);
                A2[at] = ldfragA(dH2, ab[at]);
            }
        }
        int s00 = ks * 16 + lr + lk;
        int o = s00 & 7, jb = s00 & ~7;
        const ushort_t* rb = rep + o * RSTR + jb + bofs;

        half8 B1[NT], B2[NT];
#pragma unroll
        for (int nt = 0; nt < NT; ++nt) {
            B1[nt] = ldB128(rb + nt * 32);
            B2[nt] = ldB128(rb + H2OFF + nt * 32);
        }
        half8 nA1[AT], nA2[AT];
        if (APF && ks < 31) {
#pragma unroll
            for (int at = 0; at < AT; ++at) {
                nA1[at] = ldfragA(dH1, ab[at] + 2 * NATOMS * 8);
                nA2[at] = ldfragA(dH2, ab[at] + 2 * NATOMS * 8);
            }
        }
#pragma unroll
        for (int at = 0; at < AT; ++at)
#pragma unroll
            for (int nt = 0; nt < NT; ++nt)
                acc[at][nt] = MFMA32H(A1[at], B1[nt], acc[at][nt], 0, 0, 0);
#pragma unroll
        for (int at = 0; at < AT; ++at)
#pragma unroll
            for (int nt = 0; nt < NT; ++nt)
                acc[at][nt] = MFMA32H(A1[at], B2[nt], acc[at][nt], 0, 0, 0);
#pragma unroll
        for (int at = 0; at < AT; ++at)
#pragma unroll
            for (int nt = 0; nt < NT; ++nt)
                acc[at][nt] = MFMA32H(A2[at], B1[nt], acc[at][nt], 0, 0, 0);
        if (APF && ks < 31) {
#pragma unroll
            for (int at = 0; at < AT; ++at) { A1[at] = nA1[at]; A2[at] = nA2[at]; }
        }
#pragma unroll
        for (int at = 0; at < AT; ++at) ab[at] += 2 * NATOMS * 8;
    }
}

// ---------- initial full correlation via fp16-split MFMA ----------
// grid (256 pos-tiles of 128, 8 channels, 2 atom-halves), 256 threads = 4 waves.
// wave w: atoms [half*128 + w*32, +32) x positions [qt, qt+128) (AT=1, NT=4).
__global__ __launch_bounds__(256) void init_mfma(const float* __restrict__ res,
                                                 const ushort_t* __restrict__ dH1,
                                                 const ushort_t* __restrict__ dH2,
                                                 unsigned long long* __restrict__ mkey,
                                                 unsigned long long* __restrict__ stepkey) {
    __shared__ __align__(16) ushort_t rep[REPT];
    __shared__ unsigned long long warr[512];
    __shared__ unsigned long long kred[256];
    int t = threadIdx.x;
    int qt = blockIdx.x * 128;
    int c  = blockIdx.y;
    int half = blockIdx.z;

    const float* rc_ = res + c * NLEN;
    for (int i = t; i < 656; i += 256) {
        int g = qt + i;
        float x = (g < NLEN) ? rc_[g] : 0.0f;
        stage_rep(x, i, rep);
    }
    __syncthreads();

    int wid = t >> 6, l = t & 63;
    int a0w = half * 128 + wid * 32;
    int lk = (l >> 5) * 8;
    int lr = l & 31;

    f32x16 acc[1][4];
    conv_body<1, 4, false>(dH1, dH2, rep, a0w, lr, lk, 0, acc);

    // C/D mapping (m74/m101): col=lane&31, row=(reg&3)+8*(reg>>2)+4*(lane>>5)
#pragma unroll
    for (int nt = 0; nt < 4; ++nt) {
        unsigned long long key = 0ull;
#pragma unroll
        for (int reg = 0; reg < 16; ++reg) {
            int atom = a0w + (reg & 3) + 8 * (reg >> 2) + 4 * (l >> 5);
            unsigned long long kk2 = packkey(acc[0][nt][reg], atom, qt + nt * 32 + lr);
            if (kk2 > key) key = kk2;
        }
        unsigned long long o = __shfl_xor(key, 32);
        if (o > key) key = o;
        if (l < 32) warr[wid * 128 + nt * 32 + l] = key;
    }
    __syncthreads();

    if (t < 128) {
        unsigned long long f = warr[t];
        if (warr[128 + t] > f) f = warr[128 + t];
        if (warr[256 + t] > f) f = warr[256 + t];
        if (warr[384 + t] > f) f = warr[384 + t];
        atomicMax(&mkey[c * NLEN + qt + t], f);
        kred[t] = f;
    } else kred[t] = 0ull;
    __syncthreads();
    for (int off = 128; off; off >>= 1) {
        if (t < off) { if (kred[t + off] > kred[t]) kred[t] = kred[t + off]; }
        __syncthreads();
    }
    if (t == 0) atomicMax(&stepkey[c], kred[0]);
}

// ---------- per-step kernel: 512 blocks x 256 threads ----------
// b < 256 : window MFMA blocks: c = b>>5, tile = b&31, qt = w0 + tile*32.
//           4 waves x 64 atoms (AT=2) x 32 pos (NT=1); stage buf_cur + delta_k
//           on the fly (fp32, same rounding as writer); exclusive plain mkey stores.
//           Staging trimmed to 544 elements (max needed: s00<=535, +8 span).
// b >= 256: scan blocks: c = sb>>5, seg = sb&31 (1024 pos) outside [w0,w1);
//           seg==0 blocks also advance buf_next from R_{k-1} to R_{k+1} (fp32 exact).
__global__ __launch_bounds__(256) void step_kernel(const float* __restrict__ buf_cur,
                                                   float* __restrict__ buf_next,
                                                   const float* __restrict__ d_t,
                                                   const ushort_t* __restrict__ dH1,
                                                   const ushort_t* __restrict__ dH2,
                                                   unsigned long long* __restrict__ mkey,
                                                   unsigned long long* __restrict__ stepkey,
                                                   int k) {
    int b = blockIdx.x, t = threadIdx.x;
    __shared__ __align__(16) ushort_t rep[REPT];
    __shared__ unsigned long long warr[128];
    __shared__ unsigned long long kred[256];

    if (b < 256) {
        int c = b >> 5, tile = b & 31;
        unsigned long long key = stepkey[k * NCHAN + c];
        int a = 255 - (int)((key >> 15) & 255);
        int p = (NLEN - 1) - (int)(key & 32767);
        float v = unord32((unsigned int)(key >> 23));
        int w0 = max(0, p - (ATOM_S - 1));
        int w1 = min(NLEN, p + ATOM_S);
        int qt = w0 + tile * 32;

        const float* rcur = buf_cur + c * NLEN;
        for (int i = t; i < 544; i += 256) {
            int g = qt + i;
            float x = (g < NLEN) ? rcur[g] : 0.0f;
            int s = g - p;
            if (s >= 0 && s < ATOM_S && g < NLEN) {
                float dval = d_t[((s >> 2) * NATOMS + a) * 4 + (s & 3)];
                x = __fsub_rn(x, __fmul_rn(v, dval));
            }
            stage_rep(x, i, rep);
        }
        __syncthreads();

        int wid = t >> 6, l = t & 63;
        int a0w = wid * 64;
        int lk = (l >> 5) * 8;
        int lr = l & 31;

        f32x16 acc[2][1];
        conv_body<2, 1, true>(dH1, dH2, rep, a0w, lr, lk, 0, acc);

        unsigned long long kkey = 0ull;
#pragma unroll
        for (int at = 0; at < 2; ++at)
#pragma unroll
            for (int reg = 0; reg < 16; ++reg) {
                int atom = a0w + at * 32 + (reg & 3) + 8 * (reg >> 2) + 4 * (l >> 5);
                unsigned long long kk2 = packkey(acc[at][0][reg], atom, qt + lr);
                if (kk2 > kkey) kkey = kk2;
            }
        unsigned long long o = __shfl_xor(kkey, 32);
        if (o > kkey) kkey = o;
        if (l < 32) warr[wid * 32 + l] = kkey;
        __syncthreads();

        unsigned long long myk = 0ull;
        if (t < 32) {
            unsigned long long f = warr[t];
            if (warr[32 + t] > f) f = warr[32 + t];
            if (warr[64 + t] > f) f = warr[64 + t];
            if (warr[96 + t] > f) f = warr[96 + t];
            int q = qt + t;
            if (q < w1) {                     // exclusive owner: plain store
                mkey[c * NLEN + q] = f;
                myk = f;
            }
        }
        kred[t] = myk;
        __syncthreads();
        for (int off = 128; off; off >>= 1) {
            if (t < off) { if (kred[t + off] > kred[t]) kred[t] = kred[t + off]; }
            __syncthreads();
        }
        if (t == 0) atomicMax(&stepkey[(k + 1) * NCHAN + c], kred[0]);
    } else {
        int sb = b - 256;
        int c = sb >> 5, seg = sb & 31;
        unsigned long long key = stepkey[k * NCHAN + c];
        int p = (NLEN - 1) - (int)(key & 32767);
        int w0 = max(0, p - (ATOM_S - 1));
        int w1 = min(NLEN, p + ATOM_S);

        // writer duty: bring buf_next from R_{k-1} to R_{k+1} (sequential deltas)
        if (seg == 0) {
            float* bn = buf_next + c * NLEN;
            int s0 = (k > 0) ? (k - 1) : 0;
            for (int s = s0; s <= k; ++s) {
                unsigned long long ks = stepkey[s * NCHAN + c];
                int as = 255 - (int)((ks >> 15) & 255);
                int ps = (NLEN - 1) - (int)(ks & 32767);
                float vs = unord32((unsigned int)(ks >> 23));
                for (int i = t; i < ATOM_S; i += 256) {
                    int q = ps + i;
                    if (q < NLEN) {
                        float dval = d_t[((i >> 2) * NATOMS + as) * 4 + (i & 3)];
                        bn[q] = __fsub_rn(bn[q], __fmul_rn(vs, dval));
                    }
                }
                __syncthreads();
            }
        }

        // scan duty: max over mkey outside [w0,w1), 1024 positions
        const unsigned long long* mk = mkey + c * NLEN;
        unsigned long long myk = 0ull;
        int q0 = seg * 1024;
#pragma unroll
        for (int i = 0; i < 4; ++i) {
            int q = q0 + i * 256 + t;
            if (q < w0 || q >= w1) {
                unsigned long long z = mk[q];
                if (z > myk) myk = z;
            }
        }
        kred[t] = myk;
        __syncthreads();
        for (int off = 128; off; off >>= 1) {
            if (t < off) { if (kred[t + off] > kred[t]) kred[t] = kred[t + off]; }
            __syncthreads();
        }
        if (t == 0) atomicMax(&stepkey[(k + 1) * NCHAN + c], kred[0]);
    }
}

// ---------- final loss from stepkey (one block, 256 threads) ----------
__global__ __launch_bounds__(256) void loss_kernel(const unsigned long long* __restrict__ stepkey,
                                                   float* __restrict__ out) {
    int t = threadIdx.x;
    __shared__ int   lsa[NSEL], lsp[NSEL];
    __shared__ float lsv[NSEL];
    __shared__ double red[256];
    __shared__ double smx;

    if (t < NSEL) {
        int c = t >> 4, k = t & 15;
        unsigned long long key = stepkey[k * NCHAN + c];
        lsa[t] = 255 - (int)((key >> 15) & 255);
        lsp[t] = (NLEN - 1) - (int)(key & 32767);
        lsv[t] = unord32((unsigned int)(key >> 23));
    }
    __syncthreads();

    int myc = (t < NSEL) ? (t >> 4) : -1;
    int mya = (t < NSEL) ? lsa[t] : -1;
    int myp = (t < NSEL) ? lsp[t] : -1;

    int fullowner = t;
    double fullsum = 0.0;
    if (t < NSEL) {
        for (int j = 0; j < NSEL; ++j) {
            if ((j >> 4) == myc && lsa[j] == mya && lsp[j] == myp) {
                if (j < fullowner) fullowner = j;
                fullsum += (double)lsv[j];
            }
        }
    }
    red[t] = (t < NSEL && fullowner == t) ? fullsum : 0.0;
    __syncthreads();
    for (int off = 128; off; off >>= 1) {
        if (t < off) red[t] = fmax(red[t], red[t + off]);
        __syncthreads();
    }
    if (t == 0) smx = red[0];
    __syncthreads();
    double mx = smx;

    int gowner = t;
    double rv = 0.0, tv = 0.0;
    if (t < NSEL) {
        int myb = myc & 3;
        for (int j = 0; j < NSEL; ++j) {
            int jc = j >> 4;
            if ((jc & 3) == myb && lsa[j] == mya && lsp[j] == myp) {
                if (j < gowner) gowner = j;
                if (jc < 4) rv += (double)lsv[j]; else tv += (double)lsv[j];
            }
        }
    }

    const double EPS = 1e-12;
    double bg_term = -log1p(-EPS);

    double extra = 0.0;
    if (t < NSEL && gowner == t) {
        double r = rv / mx, tt = tv / mx;
        double rc = r;
        if (rc < EPS) rc = EPS;
        if (rc > 1.0) rc = 1.0;
        double lr = log(rc);  if (lr < -100.0) lr = -100.0;
        double l1 = (rc >= 1.0) ? -100.0 : log1p(-rc);
        if (l1 < -100.0) l1 = -100.0;
        double term = -(tt * lr + (1.0 - tt) * l1);
        extra = term - bg_term;
    }

    red[t] = extra;
    __syncthreads();
    for (int off = 128; off; off >>= 1) {
        if (t < off) red[t] += red[t + off];
        __syncthreads();
    }
    if (t == 0) {
        const double count = 33554432.0;  // 4 * 256 * 32768
        double total = count * bg_term + red[0];
        out[0] = (float)(total / count);
    }
}

// ---------- launch ----------
extern "C" void kernel_launch(void* const* d_in, const int* in_sizes, int n_in,
                              void* d_out, int out_size, void* d_ws, size_t ws_size,
                              hipStream_t stream) {
    const float* recon  = (const float*)d_in[0];
    const float* target = (const float*)d_in[1];
    const float* d      = (const float*)d_in[2];
    char* ws = (char*)d_ws;
    float* d_t                    = (float*)(ws);                        // 512 KB
    float* res0                   = (float*)(ws + 524288);               // 1 MB
    float* res1                   = (float*)(ws + 1572864);              // 1 MB
    unsigned long long* mkey      = (unsigned long long*)(ws + 2621440); // 2 MB
    unsigned long long* stepkey   = (unsigned long long*)(ws + 4718592); // 1 KB
    ushort_t* dH1                 = (ushort_t*)(ws + 4719616);           // 256 KB
    ushort_t* dH2                 = (ushort_t*)(ws + 4981760);           // 256 KB
    float* out = (float*)d_out;

    hipLaunchKernelGGL(prep_kernel, dim3(NATOMS + 33), dim3(256), 0, stream,
                       recon, target, d, d_t, dH1, dH2, res0, res1, mkey, stepkey);
    hipLaunchKernelGGL(init_mfma, dim3(256, NCHAN, 2), dim3(256), 0, stream,
                       res0, dH1, dH2, mkey, stepkey);
    for (int k = 0; k < NSTEPS - 1; ++k) {
        float* cur  = (k & 1) ? res1 : res0;
        float* next = (k & 1) ? res0 : res1;
        hipLaunchKernelGGL(step_kernel, dim3(512), dim3(256), 0, stream,
                           cur, next, d_t, dH1, dH2, mkey, stepkey, k);
    }
    hipLaunchKernelGGL(loss_kernel, dim3(1), dim3(256), 0, stream,
                       stepkey, out);
}

// Round 17
// 440.152 us; speedup vs baseline: 1.4778x; 1.0119x over previous
//
#include <hip/hip_runtime.h>
#include <math.h>

#define NLEN   32768
#define NATOMS 256
#define ATOM_S 512
#define NSTEPS 16
#define NCHAN  8   // 2 signals x 4 batches
#define NSEL   (NCHAN * NSTEPS)   // 128

// 8-replica LDS geometry (ushort units), fp16 2-way split.
#define RSTR  712
#define H2OFF (8 * RSTR)           // second split region
#define REPT  (16 * RSTR)          // 11392 ushort = 22784 B

typedef unsigned short ushort_t;
typedef _Float16 half8 __attribute__((ext_vector_type(8)));
typedef __attribute__((ext_vector_type(16))) float f32x16;
#define MFMA32H __builtin_amdgcn_mfma_f32_32x32x16_f16

// ---------- packed ordered key helpers ----------
__device__ __forceinline__ unsigned int ord32(float x) {
    unsigned int u = __float_as_uint(x);
    return (u & 0x80000000u) ? ~u : (u | 0x80000000u);
}
__device__ __forceinline__ float unord32(unsigned int o) {
    unsigned int u = (o & 0x80000000u) ? (o & 0x7FFFFFFFu) : ~o;
    return __uint_as_float(u);
}
// bigger key = bigger v, then smaller atom, then smaller position
__device__ __forceinline__ unsigned long long packkey(float v, int a, int q) {
    return ((unsigned long long)ord32(v) << 23)
         | ((unsigned long long)((255 - a) & 255) << 15)
         | (unsigned long long)((NLEN - 1 - q) & 32767);
}

// ---------- fp16 split helpers (RNE) ----------
__device__ __forceinline__ ushort_t f2h(float x) {
    _Float16 h = (_Float16)x;
    return *(ushort_t*)&h;
}
__device__ __forceinline__ float h2f(ushort_t u) {
    _Float16 h = *(_Float16*)&u;
    return (float)h;
}

// ---------- prep: normalize dict; write FRAGMENT-MAJOR fp16 2-way splits ----------
__global__ void prep_kernel(const float* __restrict__ recon,
                            const float* __restrict__ target,
                            const float* __restrict__ d,
                            float* __restrict__ d_t,
                            ushort_t* __restrict__ dH1,
                            ushort_t* __restrict__ dH2,
                            float* __restrict__ res0,
                            float* __restrict__ res1,
                            unsigned long long* __restrict__ mkey,
                            unsigned long long* __restrict__ stepkey) {
    int b = blockIdx.x, t = threadIdx.x;
    if (b < NATOMS) {
        __shared__ float red[256];
        float x0 = d[b * ATOM_S + t];
        float x1 = d[b * ATOM_S + 256 + t];
        red[t] = x0 * x0 + x1 * x1;
        __syncthreads();
        for (int off = 128; off; off >>= 1) {
            if (t < off) red[t] += red[t + off];
            __syncthreads();
        }
        float denom = sqrtf(red[0]) + 1e-8f;
        float xn0 = x0 / denom, xn1 = x1 / denom;
        int s0 = t, s1 = t + 256;
        d_t[((s0 >> 2) * NATOMS + b) * 4 + (s0 & 3)] = xn0;
        d_t[((s1 >> 2) * NATOMS + b) * 4 + (s1 & 3)] = xn1;
        {
            ushort_t a1 = f2h(xn0); float r1 = xn0 - h2f(a1);
            ushort_t a2 = f2h(r1);
            int fi = ((s0 >> 3) * NATOMS + b) * 8 + (s0 & 7);
            dH1[fi] = a1; dH2[fi] = a2;
        }
        {
            ushort_t a1 = f2h(xn1); float r1 = xn1 - h2f(a1);
            ushort_t a2 = f2h(r1);
            int fi = ((s1 >> 3) * NATOMS + b) * 8 + (s1 & 7);
            dH1[fi] = a1; dH2[fi] = a2;
        }
    } else if (b < NATOMS + 32) {
        int blk = b - NATOMS;
        for (int i = 0; i < 32; ++i) {
            int idx = blk * 8192 + i * 256 + t;     // 0 .. 262143
            int c = idx >> 15, q = idx & (NLEN - 1);
            float x = (c < 4) ? recon[c * NLEN + q] : target[(c - 4) * NLEN + q];
            res0[idx] = x;
            res1[idx] = x;
            mkey[idx] = 0ull;                        // needed: init uses atomicMax
        }
    } else {
        if (t < NSEL) stepkey[t] = 0ull;
    }
}

// ---------- fragment loaders ----------
__device__ __forceinline__ half8 ldfragA(const ushort_t* __restrict__ dg, int off) {
    union { uint4 u4; half8 v; } f;
    f.u4 = *(const uint4*)(dg + off);       // 16B-aligned, wave-contiguous
    return f.v;
}
__device__ __forceinline__ half8 ldB128(const ushort_t* p) {
    union { uint4 u4; half8 v; } f;
    f.u4 = *(const uint4*)p;                // 16B-aligned by replica construction
    return f.v;
}

// ---------- stage one fp32 value into the 8-replica fp16-split LDS ----------
__device__ __forceinline__ void stage_rep(float x, int i, ushort_t* rep) {
    ushort_t h1 = f2h(x);  float x1 = x - h2f(h1);
    ushort_t h2 = f2h(x1);
#pragma unroll
    for (int o = 0; o < 8; ++o) {
        int j = i - o;
        if (j >= 0) {
            rep[o * RSTR + j]         = h1;
            rep[H2OFF + o * RSTR + j] = h2;
        }
    }
}

// ---------- MFMA conv tile: AT*32 atoms x NT*32 positions per wave ----------
// fp16 2-way split, 3 products per acc: A1B1, A1B2, A2B1 (ks ascending, fixed
// order -> deterministic). B via ds_read_b128 (8-replica LDS, stride RSTR);
// A via fragment-major coalesced global loads, double-buffered when APF.
template<int AT, int NT, bool APF>
__device__ __forceinline__ void conv_body(const ushort_t* __restrict__ dH1,
                                          const ushort_t* __restrict__ dH2,
                                          const ushort_t* rep,
                                          int a0w, int lr, int lk, int bofs,
                                          f32x16 acc[AT][NT]) {
#pragma unroll
    for (int at = 0; at < AT; ++at)
#pragma unroll
        for (int nt = 0; nt < NT; ++nt) acc[at][nt] = (f32x16)(0.0f);

    int ab[AT];
#pragma unroll
    for (int at = 0; at < AT; ++at)
        ab[at] = (((lk >> 3) * NATOMS) + a0w + at * 32 + lr) * 8;

    half8 A1[AT], A2[AT];
    if (APF) {
#pragma unroll
        for (int at = 0; at < AT; ++at) {
            A1[at] = ldfragA(dH1, ab[at]);
            A2[at] = ldfragA(dH2, ab[at]);
        }
    }

#pragma unroll 1
    for (int ks = 0; ks < 32; ++ks) {
        if (!APF) {
#pragma unroll
            for (int at = 0; at < AT; ++at) {
                A1[at] = ldfragA(dH1, ab[at]);
                A2[at] = ldfragA(dH2, ab[at]);
            }
        }
        int s00 = ks * 16 + lr + lk;
        int o = s00 & 7, jb = s00 & ~7;
        const ushort_t* rb = rep + o * RSTR + jb + bofs;

        half8 B1[NT], B2[NT];
#pragma unroll
        for (int nt = 0; nt < NT; ++nt) {
            B1[nt] = ldB128(rb + nt * 32);
            B2[nt] = ldB128(rb + H2OFF + nt * 32);
        }
        half8 nA1[AT], nA2[AT];
        if (APF && ks < 31) {
#pragma unroll
            for (int at = 0; at < AT; ++at) {
                nA1[at] = ldfragA(dH1, ab[at] + 2 * NATOMS * 8);
                nA2[at] = ldfragA(dH2, ab[at] + 2 * NATOMS * 8);
            }
        }
#pragma unroll
        for (int at = 0; at < AT; ++at)
#pragma unroll
            for (int nt = 0; nt < NT; ++nt)
                acc[at][nt] = MFMA32H(A1[at], B1[nt], acc[at][nt], 0, 0, 0);
#pragma unroll
        for (int at = 0; at < AT; ++at)
#pragma unroll
            for (int nt = 0; nt < NT; ++nt)
                acc[at][nt] = MFMA32H(A1[at], B2[nt], acc[at][nt], 0, 0, 0);
#pragma unroll
        for (int at = 0; at < AT; ++at)
#pragma unroll
            for (int nt = 0; nt < NT; ++nt)
                acc[at][nt] = MFMA32H(A2[at], B1[nt], acc[at][nt], 0, 0, 0);
        if (APF && ks < 31) {
#pragma unroll
            for (int at = 0; at < AT; ++at) { A1[at] = nA1[at]; A2[at] = nA2[at]; }
        }
#pragma unroll
        for (int at = 0; at < AT; ++at) ab[at] += 2 * NATOMS * 8;
    }
}

// ---------- initial full correlation via fp16-split MFMA ----------
// grid (256 pos-tiles of 128, 8 channels, 2 atom-halves), 256 threads = 4 waves.
// wave w: atoms [half*128 + w*32, +32) x positions [qt, qt+128) (AT=1, NT=4).
// APF=true: A fragments double-buffered across ks (hides L2 latency).
__global__ __launch_bounds__(256) void init_mfma(const float* __restrict__ res,
                                                 const ushort_t* __restrict__ dH1,
                                                 const ushort_t* __restrict__ dH2,
                                                 unsigned long long* __restrict__ mkey,
                                                 unsigned long long* __restrict__ stepkey) {
    __shared__ __align__(16) ushort_t rep[REPT];
    __shared__ unsigned long long warr[512];
    __shared__ unsigned long long kred[256];
    int t = threadIdx.x;
    int qt = blockIdx.x * 128;
    int c  = blockIdx.y;
    int half = blockIdx.z;

    const float* rc_ = res + c * NLEN;
    for (int i = t; i < 656; i += 256) {
        int g = qt + i;
        float x = (g < NLEN) ? rc_[g] : 0.0f;
        stage_rep(x, i, rep);
    }
    __syncthreads();

    int wid = t >> 6, l = t & 63;
    int a0w = half * 128 + wid * 32;
    int lk = (l >> 5) * 8;
    int lr = l & 31;

    f32x16 acc[1][4];
    conv_body<1, 4, true>(dH1, dH2, rep, a0w, lr, lk, 0, acc);

    // C/D mapping (m74/m101): col=lane&31, row=(reg&3)+8*(reg>>2)+4*(lane>>5)
#pragma unroll
    for (int nt = 0; nt < 4; ++nt) {
        unsigned long long key = 0ull;
#pragma unroll
        for (int reg = 0; reg < 16; ++reg) {
            int atom = a0w + (reg & 3) + 8 * (reg >> 2) + 4 * (l >> 5);
            unsigned long long kk2 = packkey(acc[0][nt][reg], atom, qt + nt * 32 + lr);
            if (kk2 > key) key = kk2;
        }
        unsigned long long o = __shfl_xor(key, 32);
        if (o > key) key = o;
        if (l < 32) warr[wid * 128 + nt * 32 + l] = key;
    }
    __syncthreads();

    if (t < 128) {
        unsigned long long f = warr[t];
        if (warr[128 + t] > f) f = warr[128 + t];
        if (warr[256 + t] > f) f = warr[256 + t];
        if (warr[384 + t] > f) f = warr[384 + t];
        atomicMax(&mkey[c * NLEN + qt + t], f);
        kred[t] = f;
    } else kred[t] = 0ull;
    __syncthreads();
    for (int off = 128; off; off >>= 1) {
        if (t < off) { if (kred[t + off] > kred[t]) kred[t] = kred[t + off]; }
        __syncthreads();
    }
    if (t == 0) atomicMax(&stepkey[c], kred[0]);
}

// ---------- per-step kernel: 512 blocks x 256 threads ----------
// b < 256 : window MFMA blocks: c = b>>5, tile = b&31, qt = w0 + tile*32.
//           4 waves x 64 atoms (AT=2) x 32 pos (NT=1); stage buf_cur + delta_k
//           on the fly (fp32, same rounding as writer); exclusive plain mkey stores.
// b >= 256: scan blocks: c = sb>>5, seg = sb&31 (1024 pos) outside [w0,w1);
//           seg==0 blocks also advance buf_next from R_{k-1} to R_{k+1} (fp32 exact).
__global__ __launch_bounds__(256) void step_kernel(const float* __restrict__ buf_cur,
                                                   float* __restrict__ buf_next,
                                                   const float* __restrict__ d_t,
                                                   const ushort_t* __restrict__ dH1,
                                                   const ushort_t* __restrict__ dH2,
                                                   unsigned long long* __restrict__ mkey,
                                                   unsigned long long* __restrict__ stepkey,
                                                   int k) {
    int b = blockIdx.x, t = threadIdx.x;
    __shared__ __align__(16) ushort_t rep[REPT];
    __shared__ unsigned long long warr[128];
    __shared__ unsigned long long kred[256];

    if (b < 256) {
        int c = b >> 5, tile = b & 31;
        unsigned long long key = stepkey[k * NCHAN + c];
        int a = 255 - (int)((key >> 15) & 255);
        int p = (NLEN - 1) - (int)(key & 32767);
        float v = unord32((unsigned int)(key >> 23));
        int w0 = max(0, p - (ATOM_S - 1));
        int w1 = min(NLEN, p + ATOM_S);
        int qt = w0 + tile * 32;

        const float* rcur = buf_cur + c * NLEN;
        for (int i = t; i < 544; i += 256) {
            int g = qt + i;
            float x = (g < NLEN) ? rcur[g] : 0.0f;
            int s = g - p;
            if (s >= 0 && s < ATOM_S && g < NLEN) {
                float dval = d_t[((s >> 2) * NATOMS + a) * 4 + (s & 3)];
                x = __fsub_rn(x, __fmul_rn(v, dval));
            }
            stage_rep(x, i, rep);
        }
        __syncthreads();

        int wid = t >> 6, l = t & 63;
        int a0w = wid * 64;
        int lk = (l >> 5) * 8;
        int lr = l & 31;

        f32x16 acc[2][1];
        conv_body<2, 1, true>(dH1, dH2, rep, a0w, lr, lk, 0, acc);

        unsigned long long kkey = 0ull;
#pragma unroll
        for (int at = 0; at < 2; ++at)
#pragma unroll
            for (int reg = 0; reg < 16; ++reg) {
                int atom = a0w + at * 32 + (reg & 3) + 8 * (reg >> 2) + 4 * (l >> 5);
                unsigned long long kk2 = packkey(acc[at][0][reg], atom, qt + lr);
                if (kk2 > kkey) kkey = kk2;
            }
        unsigned long long o = __shfl_xor(kkey, 32);
        if (o > kkey) kkey = o;
        if (l < 32) warr[wid * 32 + l] = kkey;
        __syncthreads();

        unsigned long long myk = 0ull;
        if (t < 32) {
            unsigned long long f = warr[t];
            if (warr[32 + t] > f) f = warr[32 + t];
            if (warr[64 + t] > f) f = warr[64 + t];
            if (warr[96 + t] > f) f = warr[96 + t];
            int q = qt + t;
            if (q < w1) {                     // exclusive owner: plain store
                mkey[c * NLEN + q] = f;
                myk = f;
            }
        }
        kred[t] = myk;
        __syncthreads();
        for (int off = 128; off; off >>= 1) {
            if (t < off) { if (kred[t + off] > kred[t]) kred[t] = kred[t + off]; }
            __syncthreads();
        }
        if (t == 0) atomicMax(&stepkey[(k + 1) * NCHAN + c], kred[0]);
    } else {
        int sb = b - 256;
        int c = sb >> 5, seg = sb & 31;
        unsigned long long key = stepkey[k * NCHAN + c];
        int p = (NLEN - 1) - (int)(key & 32767);
        int w0 = max(0, p - (ATOM_S - 1));
        int w1 = min(NLEN, p + ATOM_S);

        // writer duty: bring buf_next from R_{k-1} to R_{k+1} (sequential deltas)
        if (seg == 0) {
            float* bn = buf_next + c * NLEN;
            int s0 = (k > 0) ? (k - 1) : 0;
            for (int s = s0; s <= k; ++s) {
                unsigned long long ks = stepkey[s * NCHAN + c];
                int as = 255 - (int)((ks >> 15) & 255);
                int ps = (NLEN - 1) - (int)(ks & 32767);
                float vs = unord32((unsigned int)(ks >> 23));
                for (int i = t; i < ATOM_S; i += 256) {
                    int q = ps + i;
                    if (q < NLEN) {
                        float dval = d_t[((i >> 2) * NATOMS + as) * 4 + (i & 3)];
                        bn[q] = __fsub_rn(bn[q], __fmul_rn(vs, dval));
                    }
                }
                __syncthreads();
            }
        }

        // scan duty: max over mkey outside [w0,w1), 1024 positions
        const unsigned long long* mk = mkey + c * NLEN;
        unsigned long long myk = 0ull;
        int q0 = seg * 1024;
#pragma unroll
        for (int i = 0; i < 4; ++i) {
            int q = q0 + i * 256 + t;
            if (q < w0 || q >= w1) {
                unsigned long long z = mk[q];
                if (z > myk) myk = z;
            }
        }
        kred[t] = myk;
        __syncthreads();
        for (int off = 128; off; off >>= 1) {
            if (t < off) { if (kred[t + off] > kred[t]) kred[t] = kred[t + off]; }
            __syncthreads();
        }
        if (t == 0) atomicMax(&stepkey[(k + 1) * NCHAN + c], kred[0]);
    }
}

// ---------- final loss from stepkey (one block, 256 threads) ----------
__global__ __launch_bounds__(256) void loss_kernel(const unsigned long long* __restrict__ stepkey,
                                                   float* __restrict__ out) {
    int t = threadIdx.x;
    __shared__ int   lsa[NSEL], lsp[NSEL];
    __shared__ float lsv[NSEL];
    __shared__ double red[256];
    __shared__ double smx;

    if (t < NSEL) {
        int c = t >> 4, k = t & 15;
        unsigned long long key = stepkey[k * NCHAN + c];
        lsa[t] = 255 - (int)((key >> 15) & 255);
        lsp[t] = (NLEN - 1) - (int)(key & 32767);
        lsv[t] = unord32((unsigned int)(key >> 23));
    }
    __syncthreads();

    int myc = (t < NSEL) ? (t >> 4) : -1;
    int mya = (t < NSEL) ? lsa[t] : -1;
    int myp = (t < NSEL) ? lsp[t] : -1;

    int fullowner = t;
    double fullsum = 0.0;
    if (t < NSEL) {
        for (int j = 0; j < NSEL; ++j) {
            if ((j >> 4) == myc && lsa[j] == mya && lsp[j] == myp) {
                if (j < fullowner) fullowner = j;
                fullsum += (double)lsv[j];
            }
        }
    }
    red[t] = (t < NSEL && fullowner == t) ? fullsum : 0.0;
    __syncthreads();
    for (int off = 128; off; off >>= 1) {
        if (t < off) red[t] = fmax(red[t], red[t + off]);
        __syncthreads();
    }
    if (t == 0) smx = red[0];
    __syncthreads();
    double mx = smx;

    int gowner = t;
    double rv = 0.0, tv = 0.0;
    if (t < NSEL) {
        int myb = myc & 3;
        for (int j = 0; j < NSEL; ++j) {
            int jc = j >> 4;
            if ((jc & 3) == myb && lsa[j] == mya && lsp[j] == myp) {
                if (j < gowner) gowner = j;
                if (jc < 4) rv += (double)lsv[j]; else tv += (double)lsv[j];
            }
        }
    }

    const double EPS = 1e-12;
    double bg_term = -log1p(-EPS);

    double extra = 0.0;
    if (t < NSEL && gowner == t) {
        double r = rv / mx, tt = tv / mx;
        double rc = r;
        if (rc < EPS) rc = EPS;
        if (rc > 1.0) rc = 1.0;
        double lr = log(rc);  if (lr < -100.0) lr = -100.0;
        double l1 = (rc >= 1.0) ? -100.0 : log1p(-rc);
        if (l1 < -100.0) l1 = -100.0;
        double term = -(tt * lr + (1.0 - tt) * l1);
        extra = term - bg_term;
    }

    red[t] = extra;
    __syncthreads();
    for (int off = 128; off; off >>= 1) {
        if (t < off) red[t] += red[t + off];
        __syncthreads();
    }
    if (t == 0) {
        const double count = 33554432.0;  // 4 * 256 * 32768
        double total = count * bg_term + red[0];
        out[0] = (float)(total / count);
    }
}

// ---------- launch ----------
extern "C" void kernel_launch(void* const* d_in, const int* in_sizes, int n_in,
                              void* d_out, int out_size, void* d_ws, size_t ws_size,
                              hipStream_t stream) {
    const float* recon  = (const float*)d_in[0];
    const float* target = (const float*)d_in[1];
    const float* d      = (const float*)d_in[2];
    char* ws = (char*)d_ws;
    float* d_t                    = (float*)(ws);                        // 512 KB
    float* res0                   = (float*)(ws + 524288);               // 1 MB
    float* res1                   = (float*)(ws + 1572864);              // 1 MB
    unsigned long long* mkey      = (unsigned long long*)(ws + 2621440); // 2 MB
    unsigned long long* stepkey   = (unsigned long long*)(ws + 4718592); // 1 KB
    ushort_t* dH1                 = (ushort_t*)(ws + 4719616);           // 256 KB
    ushort_t* dH2                 = (ushort_t*)(ws + 4981760);           // 256 KB
    float* out = (float*)d_out;

    hipLaunchKernelGGL(prep_kernel, dim3(NATOMS + 33), dim3(256), 0, stream,
                       recon, target, d, d_t, dH1, dH2, res0, res1, mkey, stepkey);
    hipLaunchKernelGGL(init_mfma, dim3(256, NCHAN, 2), dim3(256), 0, stream,
                       res0, dH1, dH2, mkey, stepkey);
    for (int k = 0; k < NSTEPS - 1; ++k) {
        float* cur  = (k & 1) ? res1 : res0;
        float* next = (k & 1) ? res0 : res1;
        hipLaunchKernelGGL(step_kernel, dim3(512), dim3(256), 0, stream,
                           cur, next, d_t, dH1, dH2, mkey, stepkey, k);
    }
    hipLaunchKernelGGL(loss_kernel, dim3(1), dim3(256), 0, stream,
                       stepkey, out);
}